// Round 12
// baseline (340.697 us; speedup 1.0000x reference)
//
#include <hip/hip_runtime.h>

#define D_MODEL 1024
#define D_FFN   4096
#define NH      16
#define DH      64
#define BB      2
#define LL      2048
#define MROWS   (BB * LL)   // 4096

typedef unsigned short u16;
typedef unsigned int   u32;
typedef short bf16x8 __attribute__((ext_vector_type(8)));
typedef float f32x4  __attribute__((ext_vector_type(4)));

__device__ __forceinline__ float bf2f(u16 u) {
    union { u32 i; float f; } v;
    v.i = ((u32)u) << 16;
    return v.f;
}
__device__ __forceinline__ u16 f2bf(float f) {
    union { float f; u32 i; } v;
    v.f = f;
    u32 x = v.i;
    x += 0x7fffu + ((x >> 16) & 1u);   // round to nearest even
    return (u16)(x >> 16);
}
// pack high-16s of two floats (truncating bf16): {lo=a, hi=b}
__device__ __forceinline__ u32 pack_bf_trunc(float a, float b) {
    return __builtin_amdgcn_perm(__float_as_uint(b), __float_as_uint(a),
                                 0x07060302u);
}

// async global->LDS, 16B per lane; ldsptr must be wave-uniform (HW adds lane*16)
typedef const __attribute__((address_space(1))) u32 gu32;
typedef __attribute__((address_space(3))) u32 lu32;
__device__ __forceinline__ void gload_lds16(const void* g, void* l) {
    __builtin_amdgcn_global_load_lds((gu32*)g, (lu32*)l, 16, 0, 0);
}

// ---------------------------------------------------------------------------
// 64x64 fp32->bf16 transpose tile helper (LDS tile passed in)
// ---------------------------------------------------------------------------
__device__ __forceinline__ void wt_tile(
    const float* __restrict__ W, u16* __restrict__ Wt,
    int K, int N, int t, int tid, float* tile /* 64*65 floats */)
{
    const int ntiles = N >> 6;
    const int n0 = (t % ntiles) * 64;
    const int k0 = (t / ntiles) * 64;

    int kr = tid >> 4;             // 0..15
    int nc = (tid & 15) * 4;       // 0..60
    #pragma unroll
    for (int p = 0; p < 4; ++p) {
        float4 v = *(const float4*)&W[(size_t)(k0 + kr + p * 16) * N + n0 + nc];
        tile[(kr + p * 16) * 65 + nc + 0] = v.x;
        tile[(kr + p * 16) * 65 + nc + 1] = v.y;
        tile[(kr + p * 16) * 65 + nc + 2] = v.z;
        tile[(kr + p * 16) * 65 + nc + 3] = v.w;
    }
    __syncthreads();

    int nr = tid >> 2;             // 0..63
    int kc = (tid & 3) * 16;       // 0..48
    u16 o[16];
    #pragma unroll
    for (int j = 0; j < 16; ++j) o[j] = f2bf(tile[(kc + j) * 65 + nr]);
    u16* dst = &Wt[(size_t)(n0 + nr) * K + k0 + kc];
    *(uint4*)dst       = *(const uint4*)&o[0];
    *(uint4*)(dst + 8) = *(const uint4*)&o[8];
}

// ---------------------------------------------------------------------------
// Prep: blocks [0,2048) convert x fp32->bf16; [2048,2816) transpose Wqkv.
// ---------------------------------------------------------------------------
__global__ __launch_bounds__(256) void prep_kernel(
    const float* __restrict__ x,    u16* __restrict__ xb,
    const float* __restrict__ Wqkv, u16* __restrict__ Wqkvt)
{
    __shared__ float tile[64 * 65];
    const int tid = threadIdx.x;
    const int bi  = blockIdx.x;

    if (bi < 2048) {   // x convert
        int i = bi * 2048 + tid * 8;
        float4 a = *(const float4*)(x + i);
        float4 b = *(const float4*)(x + i + 4);
        u16 o[8] = {f2bf(a.x), f2bf(a.y), f2bf(a.z), f2bf(a.w),
                    f2bf(b.x), f2bf(b.y), f2bf(b.z), f2bf(b.w)};
        *(uint4*)(xb + i) = *(const uint4*)o;
        return;
    }
    wt_tile(Wqkv, Wqkvt, 1024, 3072, bi - 2048, tid, tile);
}

// ---------------------------------------------------------------------------
// MFMA bf16 GEMM, m97-style, XCD remap, optional split-K (see R6/R7 notes).
// EPI 0: scatter Q(x0.125*log2e)/K/V bf16 (out0v/out1/out2), N=3072
// EPI 2: ReLU, store out0v (OF32)
// EPI 3: bf16 partial (no bias) -> out0v[s*M*N + ...]
// ---------------------------------------------------------------------------
template <int EPI, int RF32, int OF32, int KS>
__global__ __launch_bounds__(256) void gemm_bt_kernel(
    const u16* __restrict__ A, const u16* __restrict__ Bt,
    const float* __restrict__ bias, const void* __restrict__ resv,
    void* __restrict__ out0v, u16* __restrict__ out1, u16* __restrict__ out2,
    int M, int N, int K)
{
    __shared__ u16 sA[128 * 64];   // 16 KB, swizzled chunk layout
    __shared__ u16 sB[128 * 64];   // 16 KB

    const int tid  = threadIdx.x;
    const int lane = tid & 63;
    const int wave = tid >> 6;
    const int wm   = (wave & 1) * 64;
    const int wn   = (wave >> 1) * 64;
    const int quad = lane >> 4;
    const int l16  = lane & 15;

    // XCD-locality remap (requires gridDim.x % 2 == 0, gridDim.y % 4 == 0)
    const int nb  = gridDim.x;
    const int mb  = gridDim.y;
    const int f   = blockIdx.y * nb + blockIdx.x;   // dispatch-linear id
    const int xcd = f & 7;
    const int idx = f >> 3;
    const int rn  = nb >> 1;                        // region width  (tiles)
    const int rm  = mb >> 2;                        // region height (tiles)
    const int n0  = ((xcd & 1) * rn + (idx % rn)) * 128;
    const int ym  = (xcd >> 1) * rm + (idx / rn);   // 0..mb-1

    int s, m0;
    if (KS > 1) {
        const int mt = mb / KS;
        s  = ym / mt;
        m0 = (ym % mt) * 128;
    } else {
        s  = 0;
        m0 = ym * 128;
    }
    const int Kseg = K / KS;
    const int kbeg = s * Kseg;

    f32x4 acc[4][4];
    #pragma unroll
    for (int i = 0; i < 4; ++i)
        #pragma unroll
        for (int j = 0; j < 4; ++j)
            acc[i][j] = (f32x4){0.f, 0.f, 0.f, 0.f};

    const u16* Ablk = A  + (size_t)m0 * K;
    const u16* Bblk = Bt + (size_t)n0 * K;

    for (int k0 = kbeg; k0 < kbeg + Kseg; k0 += 64) {
        #pragma unroll
        for (int i = 0; i < 4; ++i) {
            int chunk = (i * 4 + wave) * 64 + lane;        // 0..1023
            int r = chunk >> 3;                            // row 0..127
            int c = (chunk & 7) ^ (r & 7);                 // swizzled k-chunk
            size_t goff = (size_t)r * K + k0 + c * 8;
            gload_lds16(Ablk + goff, &sA[(i * 4 + wave) * 512]);
            gload_lds16(Bblk + goff, &sB[(i * 4 + wave) * 512]);
        }
        __syncthreads();

        #pragma unroll
        for (int ks = 0; ks < 2; ++ks) {
            bf16x8 af[4], bfr[4];
            #pragma unroll
            for (int i = 0; i < 4; ++i) {
                int R = wm + i * 16 + l16;
                int slot = R * 8 + ((ks * 4 + quad) ^ (R & 7));
                af[i] = *(const bf16x8*)&sA[slot * 8];
            }
            #pragma unroll
            for (int j = 0; j < 4; ++j) {
                int R = wn + j * 16 + l16;
                int slot = R * 8 + ((ks * 4 + quad) ^ (R & 7));
                bfr[j] = *(const bf16x8*)&sB[slot * 8];
            }
            #pragma unroll
            for (int i = 0; i < 4; ++i)
                #pragma unroll
                for (int j = 0; j < 4; ++j)
                    acc[i][j] = __builtin_amdgcn_mfma_f32_16x16x32_bf16(
                        af[i], bfr[j], acc[i][j], 0, 0, 0);
        }
        __syncthreads();
    }

    #pragma unroll
    for (int i = 0; i < 4; ++i) {
        int rowb = m0 + wm + i * 16 + quad * 4;
        #pragma unroll
        for (int j = 0; j < 4; ++j) {
            int col = n0 + wn + j * 16 + l16;
            float bv = (EPI == 3) ? 0.f : bias[col];
            #pragma unroll
            for (int r = 0; r < 4; ++r) {
                int rr = rowb + r;
                float v = acc[i][j][r] + bv;
                if (EPI == 0) {
                    int which = col >> 10;
                    int h     = (col >> 6) & 15;
                    int d     = col & 63;
                    int b     = rr >> 11;
                    int l     = rr & 2047;
                    size_t idx2 = ((size_t)(b * NH + h) * LL + l) * DH + d;
                    u16* o0 = (u16*)out0v;
                    // Q pre-scaled by 0.125 * log2(e) so attention can use
                    // exp2 directly (softmax is scale-consistent).
                    if (which == 0)      o0[idx2]   = f2bf(v * 0.18033688f);
                    else if (which == 1) out1[idx2] = f2bf(v);
                    else                 out2[idx2] = f2bf(v);
                } else if (EPI == 3) {
                    ((u16*)out0v)[((size_t)s * M + rr) * N + col] = f2bf(v);
                } else {
                    size_t idx2 = (size_t)rr * N + col;
                    if (EPI == 1) {
                        v += RF32 ? ((const float*)resv)[idx2]
                                  : bf2f(((const u16*)resv)[idx2]);
                    } else {  // EPI == 2: ReLU
                        v = v > 0.f ? v : 0.f;
                    }
                    if (OF32) ((float*)out0v)[idx2] = v;
                    else      ((u16*)out0v)[idx2]   = f2bf(v);
                }
            }
        }
    }
}

// ---------------------------------------------------------------------------
// Fused split-K reduce + LayerNorm. One block per row.
// ---------------------------------------------------------------------------
template <int KS, int RF32, int OF32>
__global__ __launch_bounds__(256) void lnfuse_kernel(
    const u16* __restrict__ P, const float* __restrict__ bias,
    const void* __restrict__ resv,
    const float* __restrict__ ga, const float* __restrict__ gb,
    void* __restrict__ outv)
{
    __shared__ float red[8];
    const int tid  = threadIdx.x;
    const int lane = tid & 63;
    const int wave = tid >> 6;
    const size_t row = blockIdx.x;
    const size_t SL  = (size_t)MROWS * D_MODEL;
    const int c = tid * 4;

    float v0, v1, v2, v3;
    {
        float4 bv = *(const float4*)(bias + c);
        v0 = bv.x; v1 = bv.y; v2 = bv.z; v3 = bv.w;
    }
    #pragma unroll
    for (int s = 0; s < KS; ++s) {
        uint2 p = *(const uint2*)(P + s * SL + row * D_MODEL + c);
        v0 += bf2f((u16)p.x); v1 += bf2f((u16)(p.x >> 16));
        v2 += bf2f((u16)p.y); v3 += bf2f((u16)(p.y >> 16));
    }
    if (RF32) {
        float4 r = *(const float4*)((const float*)resv + row * D_MODEL + c);
        v0 += r.x; v1 += r.y; v2 += r.z; v3 += r.w;
    } else {
        uint2 r = *(const uint2*)((const u16*)resv + row * D_MODEL + c);
        v0 += bf2f((u16)r.x); v1 += bf2f((u16)(r.x >> 16));
        v2 += bf2f((u16)r.y); v3 += bf2f((u16)(r.y >> 16));
    }

    float s_ = v0 + v1 + v2 + v3;
    #pragma unroll
    for (int o = 32; o > 0; o >>= 1) s_ += __shfl_xor(s_, o, 64);
    if (lane == 0) red[wave] = s_;
    __syncthreads();
    float mean = (red[0] + red[1] + red[2] + red[3]) * (1.f / 1024.f);

    float d0 = v0 - mean, d1 = v1 - mean, d2 = v2 - mean, d3 = v3 - mean;
    float q = d0 * d0 + d1 * d1 + d2 * d2 + d3 * d3;
    #pragma unroll
    for (int o = 32; o > 0; o >>= 1) q += __shfl_xor(q, o, 64);
    if (lane == 0) red[4 + wave] = q;
    __syncthreads();
    float var = (red[4] + red[5] + red[6] + red[7]) * (1.f / 1023.f);
    float inv = 1.f / (sqrtf(var) + 1e-6f);

    float y0 = d0 * inv * ga[c + 0] + gb[c + 0];
    float y1 = d1 * inv * ga[c + 1] + gb[c + 1];
    float y2 = d2 * inv * ga[c + 2] + gb[c + 2];
    float y3 = d3 * inv * ga[c + 3] + gb[c + 3];
    if (OF32) {
        float4 y = {y0, y1, y2, y3};
        *(float4*)((float*)outv + row * D_MODEL + c) = y;
    } else {
        ushort4 y = {f2bf(y0), f2bf(y1), f2bf(y2), f2bf(y3)};
        *(ushort4*)((u16*)outv + row * D_MODEL + c) = y;
    }
}

// ---------------------------------------------------------------------------
// MFMA flash attention (causal, R9 structure) + FOLDED WEIGHT TRANSPOSES:
// blocks [0,512): attention (balanced pairs, XCD remap, register prefetch);
// blocks [512,2816): Wo/W1/W2 64x64 transpose tiles (fills idle CU slots).
// Softmax uses exp2 (Q pre-scaled by 0.125*log2e at QKV epilogue) — removes
// the v_mul(log2e) from every exp in the per-chunk serial chain.
// ---------------------------------------------------------------------------
__global__ __launch_bounds__(256) void attn_kernel(
    const u16* __restrict__ Q, const u16* __restrict__ K,
    const u16* __restrict__ V, u16* __restrict__ out,
    const float* __restrict__ Wo, u16* __restrict__ Wot,
    const float* __restrict__ W1, u16* __restrict__ W1t,
    const float* __restrict__ W2, u16* __restrict__ W2t)
{
    __shared__ u16 smem[18432];   // 36864 B: ks|vs|ps for attn, tile for wt
    u16* ks = smem;                       // 64*72
    u16* vs = smem + 4608;                // 64*72
    u16* ps = smem + 9216;                // 4 waves * 2 tiles * 16*72

    const int tid  = threadIdx.x;
    const int bi   = blockIdx.x;

    if (bi >= 512) {   // ---- weight transpose blocks ----
        float* tile = (float*)smem;       // 64*65 floats = 16640 B
        int t = bi - 512;
        if (t < 256)       wt_tile(Wo, Wot, 1024, 1024, t,        tid, tile);
        else if (t < 1280) wt_tile(W1, W1t, 1024, 4096, t - 256,  tid, tile);
        else               wt_tile(W2, W2t, 4096, 1024, t - 1280, tid, tile);
        return;
    }

    const int lane = tid & 63;
    const int wave = tid >> 6;
    const int l16  = lane & 15;
    const int quad = lane >> 4;

    const int f   = bi;                 // 0..511
    const int xcd = f & 7;
    const int idx = f >> 3;             // 0..63
    const int bh  = xcd * 4 + (idx >> 4);
    const int pr  = idx & 15;
    const int b   = bh >> 4, h = bh & 15;
    const size_t head_off = (size_t)bh * LL * DH;

    const u16* Qh = Q + head_off;
    const u16* Kh = K + head_off;
    const u16* Vh = V + head_off;

    const int qtA = 31 - pr, qtB = pr;
    const int baseA = qtA * 64 + wave * 16;
    const int baseB = qtB * 64 + wave * 16;
    const int qgA   = baseA + l16;
    const int qgB   = baseB + l16;

    const bf16x8 qfA0 = *(const bf16x8*)&Qh[(size_t)qgA * DH + quad * 8];
    const bf16x8 qfA1 = *(const bf16x8*)&Qh[(size_t)qgA * DH + 32 + quad * 8];
    const bf16x8 qfB0 = *(const bf16x8*)&Qh[(size_t)qgB * DH + quad * 8];
    const bf16x8 qfB1 = *(const bf16x8*)&Qh[(size_t)qgB * DH + 32 + quad * 8];

    float lA = 0.f, lB = 0.f;
    f32x4 oA[4], oB[4];
    #pragma unroll
    for (int t = 0; t < 4; ++t) {
        oA[t] = (f32x4){0.f, 0.f, 0.f, 0.f};
        oB[t] = (f32x4){0.f, 0.f, 0.f, 0.f};
    }

    u16* psA = ps + wave * 2304;          // 2 * 16*72 per wave
    u16* psB = psA + 1152;

    const int key = tid >> 2;            // 0..63
    const int kd0 = (tid & 3) * 16;      // 0,16,32,48
    const int kp  = tid >> 3;            // 0..31 (key pair)
    const int vd0 = (tid & 7) * 8;       // 0..56

    uint4 kr0, kr1, vr0, vr1;
    {
        const u16* ksrc = Kh + (size_t)key * DH + kd0;
        kr0 = *(const uint4*)ksrc;
        kr1 = *(const uint4*)(ksrc + 8);
        const u16* vsrc = Vh + (size_t)(2 * kp) * DH + vd0;
        vr0 = *(const uint4*)vsrc;
        vr1 = *(const uint4*)(vsrc + DH);
    }

    for (int c = 0; c <= qtA; ++c) {
        const bool doB = (c <= qtB);
        __syncthreads();
        *(uint4*)&ks[key * 72 + kd0]     = kr0;
        *(uint4*)&ks[key * 72 + kd0 + 8] = kr1;
        {
            const u32* w0 = (const u32*)&vr0;
            const u32* w1 = (const u32*)&vr1;
            #pragma unroll
            for (int e = 0; e < 8; ++e) {
                int d = vd0 + e;
                u32 lo = (w0[e >> 1] >> ((e & 1) * 16)) & 0xffffu;
                u32 hi = (w1[e >> 1] >> ((e & 1) * 16)) & 0xffffu;
                int csw = kp ^ (4 * ((d >> 3) & 7));
                *(u32*)&vs[d * 72 + 2 * csw] = lo | (hi << 16);
            }
        }
        __syncthreads();
        if (c < qtA) {
            const u16* ksrc = Kh + (size_t)((c + 1) * 64 + key) * DH + kd0;
            kr0 = *(const uint4*)ksrc;
            kr1 = *(const uint4*)(ksrc + 8);
            const u16* vsrc = Vh + (size_t)((c + 1) * 64 + 2 * kp) * DH + vd0;
            vr0 = *(const uint4*)vsrc;
            vr1 = *(const uint4*)(vsrc + DH);
        }

        f32x4 stA[4], stB[4];
        #pragma unroll
        for (int t = 0; t < 4; ++t) {
            bf16x8 k0 = *(const bf16x8*)&ks[(t * 16 + l16) * 72 + quad * 8];
            bf16x8 k1 = *(const bf16x8*)&ks[(t * 16 + l16) * 72 + 32 + quad * 8];
            f32x4 s = (f32x4){0.f, 0.f, 0.f, 0.f};
            s = __builtin_amdgcn_mfma_f32_16x16x32_bf16(k0, qfA0, s, 0, 0, 0);
            s = __builtin_amdgcn_mfma_f32_16x16x32_bf16(k1, qfA1, s, 0, 0, 0);
            stA[t] = s;
            if (doB) {
                f32x4 s2 = (f32x4){0.f, 0.f, 0.f, 0.f};
                s2 = __builtin_amdgcn_mfma_f32_16x16x32_bf16(k0, qfB0, s2, 0, 0, 0);
                s2 = __builtin_amdgcn_mfma_f32_16x16x32_bf16(k1, qfB1, s2, 0, 0, 0);
                stB[t] = s2;
            }
        }

        if (c == qtA) {
            #pragma unroll
            for (int t = 0; t < 4; ++t)
                #pragma unroll
                for (int r = 0; r < 4; ++r)
                    if (c * 64 + t * 16 + quad * 4 + r > qgA) stA[t][r] = -INFINITY;
        }
        if (doB && c == qtB) {
            #pragma unroll
            for (int t = 0; t < 4; ++t)
                #pragma unroll
                for (int r = 0; r < 4; ++r)
                    if (c * 64 + t * 16 + quad * 4 + r > qgB) stB[t][r] = -INFINITY;
        }

        {
            float psum = 0.f;
            #pragma unroll
            for (int t = 0; t < 4; ++t) {
                float p0 = exp2f(stA[t][0]), p1 = exp2f(stA[t][1]);
                float p2 = exp2f(stA[t][2]), p3 = exp2f(stA[t][3]);
                psum += (p0 + p1) + (p2 + p3);
                uint2 w = {pack_bf_trunc(p0, p1), pack_bf_trunc(p2, p3)};
                *(uint2*)&psA[l16 * 72 + t * 16 + quad * 4] = w;
            }
            psum += __shfl_xor(psum, 16, 64);
            psum += __shfl_xor(psum, 32, 64);
            lA += psum;
        }
        if (doB) {
            float psum = 0.f;
            #pragma unroll
            for (int t = 0; t < 4; ++t) {
                float p0 = exp2f(stB[t][0]), p1 = exp2f(stB[t][1]);
                float p2 = exp2f(stB[t][2]), p3 = exp2f(stB[t][3]);
                psum += (p0 + p1) + (p2 + p3);
                uint2 w = {pack_bf_trunc(p0, p1), pack_bf_trunc(p2, p3)};
                *(uint2*)&psB[l16 * 72 + t * 16 + quad * 4] = w;
            }
            psum += __shfl_xor(psum, 16, 64);
            psum += __shfl_xor(psum, 32, 64);
            lB += psum;
        }

        bf16x8 pfA0 = *(const bf16x8*)&psA[l16 * 72 + quad * 8];
        bf16x8 pfA1 = *(const bf16x8*)&psA[l16 * 72 + 32 + quad * 8];
        bf16x8 pfB0, pfB1;
        if (doB) {
            pfB0 = *(const bf16x8*)&psB[l16 * 72 + quad * 8];
            pfB1 = *(const bf16x8*)&psB[l16 * 72 + 32 + quad * 8];
        }

        #pragma unroll
        for (int dt = 0; dt < 4; ++dt) {
            int d  = dt * 16 + l16;
            int sw = 4 * ((d >> 3) & 7);
            bf16x8 vf0 = *(const bf16x8*)&vs[d * 72 + 2 * ((quad * 4) ^ sw)];
            bf16x8 vf1 = *(const bf16x8*)&vs[d * 72 + 2 * ((16 + quad * 4) ^ sw)];
            oA[dt] = __builtin_amdgcn_mfma_f32_16x16x32_bf16(pfA0, vf0, oA[dt], 0, 0, 0);
            oA[dt] = __builtin_amdgcn_mfma_f32_16x16x32_bf16(pfA1, vf1, oA[dt], 0, 0, 0);
            if (doB) {
                oB[dt] = __builtin_amdgcn_mfma_f32_16x16x32_bf16(pfB0, vf0, oB[dt], 0, 0, 0);
                oB[dt] = __builtin_amdgcn_mfma_f32_16x16x32_bf16(pfB1, vf1, oB[dt], 0, 0, 0);
            }
        }
    }

    {
        float i0 = 1.f / __shfl(lA, quad * 4 + 0, 64);
        float i1 = 1.f / __shfl(lA, quad * 4 + 1, 64);
        float i2 = 1.f / __shfl(lA, quad * 4 + 2, 64);
        float i3 = 1.f / __shfl(lA, quad * 4 + 3, 64);
        #pragma unroll
        for (int dt = 0; dt < 4; ++dt) {
            size_t col = h * DH + dt * 16 + l16;
            size_t r0  = ((size_t)b * LL + baseA + quad * 4) * D_MODEL + col;
            out[r0]               = f2bf(oA[dt][0] * i0);
            out[r0 + D_MODEL]     = f2bf(oA[dt][1] * i1);
            out[r0 + 2 * D_MODEL] = f2bf(oA[dt][2] * i2);
            out[r0 + 3 * D_MODEL] = f2bf(oA[dt][3] * i3);
        }
    }
    {
        float i0 = 1.f / __shfl(lB, quad * 4 + 0, 64);
        float i1 = 1.f / __shfl(lB, quad * 4 + 1, 64);
        float i2 = 1.f / __shfl(lB, quad * 4 + 2, 64);
        float i3 = 1.f / __shfl(lB, quad * 4 + 3, 64);
        #pragma unroll
        for (int dt = 0; dt < 4; ++dt) {
            size_t col = h * DH + dt * 16 + l16;
            size_t r0  = ((size_t)b * LL + baseB + quad * 4) * D_MODEL + col;
            out[r0]               = f2bf(oB[dt][0] * i0);
            out[r0 + D_MODEL]     = f2bf(oB[dt][1] * i1);
            out[r0 + 2 * D_MODEL] = f2bf(oB[dt][2] * i2);
            out[r0 + 3 * D_MODEL] = f2bf(oB[dt][3] * i3);
        }
    }
}

// ---------------------------------------------------------------------------
extern "C" void kernel_launch(void* const* d_in, const int* in_sizes, int n_in,
                              void* d_out, int out_size, void* d_ws, size_t ws_size,
                              hipStream_t stream)
{
    const float* x    = (const float*)d_in[0];
    // d_in[1] = mask (int32) — causal, handled analytically
    const float* Wqkv = (const float*)d_in[2];
    const float* bqkv = (const float*)d_in[3];
    const float* Wo   = (const float*)d_in[4];
    const float* bo   = (const float*)d_in[5];
    const float* W1   = (const float*)d_in[6];
    const float* b1   = (const float*)d_in[7];
    const float* W2   = (const float*)d_in[8];
    const float* b2   = (const float*)d_in[9];
    const float* ln1a = (const float*)d_in[10];
    const float* ln1b = (const float*)d_in[11];
    const float* ln2a = (const float*)d_in[12];
    const float* ln2b = (const float*)d_in[13];

    char* ws = (char*)d_ws;
    const size_t HSZ = (size_t)BB * NH * LL * DH;      // 4,194,304 elems
    u16*   Qp    = (u16*)ws;
    u16*   Kp    = Qp + HSZ;
    u16*   Vp    = Kp + HSZ;
    u16*   attn  = Vp + HSZ;
    u16*   hbuf  = (u16*)ws;                               // alias (QKV/attn dead)
    u16*   xb    = (u16*)(ws + 33554432);                  // bf16 x, 8 MB
    u16*   x1    = (u16*)(ws + 50331648);                  // bf16, 8 MB
    u16*   Wqkvt = (u16*)(ws + 58720256);                  // 3072x1024 bf16
    u16*   Wot   = (u16*)(ws + 65011712);                  // 1024x1024 bf16
    u16*   W1t   = (u16*)(ws + 67108864);                  // 4096x1024 bf16
    u16*   W2t   = (u16*)(ws + 75497472);                  // 1024x4096 bf16
    u16*   Pbuf  = (u16*)(ws + 83886080);                  // up to 4x 4096x1024 bf16

    dim3 blk(256);

    // 0) prep: x->bf16 + Wqkv transpose (only what QKV GEMM needs)
    prep_kernel<<<dim3(2816), blk, 0, stream>>>(x, xb, Wqkv, Wqkvt);

    // 1) qkv = x @ Wqkv + bqkv -> scatter Q(*0.125*log2e), K, V (bf16)
    gemm_bt_kernel<0,0,0,1><<<dim3(24, 32), blk, 0, stream>>>(
        xb, Wqkvt, bqkv, nullptr, Qp, Kp, Vp, MROWS, 3 * D_MODEL, D_MODEL);
    // 2) attention -> attn bf16; folds Wo/W1/W2 transposes into idle slots
    attn_kernel<<<dim3(2816), blk, 0, stream>>>(
        Qp, Kp, Vp, attn, Wo, Wot, W1, W1t, W2, W2t);
    // 3) Wo partials (split-K=2)
    gemm_bt_kernel<3,0,0,2><<<dim3(8, 64), blk, 0, stream>>>(
        attn, Wot, bo, nullptr, Pbuf, nullptr, nullptr, MROWS, D_MODEL, D_MODEL);
    // 4) x1 = LN1(sum(P) + bo + x)  (fused reduce+LN, bf16 out)
    lnfuse_kernel<2,1,0><<<dim3(MROWS), blk, 0, stream>>>(
        Pbuf, bo, x, ln1a, ln1b, x1);
    // 5) h = relu(x1 @ W1 + b1)  (bf16 out)
    gemm_bt_kernel<2,0,0,1><<<dim3(32, 32), blk, 0, stream>>>(
        x1, W1t, b1, nullptr, hbuf, nullptr, nullptr, MROWS, D_FFN, D_MODEL);
    // 6) W2 partials (split-K=4)
    gemm_bt_kernel<3,0,0,4><<<dim3(8, 128), blk, 0, stream>>>(
        hbuf, W2t, b2, nullptr, Pbuf, nullptr, nullptr, MROWS, D_MODEL, D_FFN);
    // 7) out = LN2(sum(P) + b2 + x1)  (fused reduce+LN, fp32 out)
    lnfuse_kernel<4,0,1><<<dim3(MROWS), blk, 0, stream>>>(
        Pbuf, b2, x1, ln2a, ln2b, d_out);
}

// Round 13
// 320.936 us; speedup vs baseline: 1.0616x; 1.0616x over previous
//
#include <hip/hip_runtime.h>

#define D_MODEL 1024
#define D_FFN   4096
#define NH      16
#define DH      64
#define BB      2
#define LL      2048
#define MROWS   (BB * LL)   // 4096

typedef unsigned short u16;
typedef unsigned int   u32;
typedef short bf16x8 __attribute__((ext_vector_type(8)));
typedef float f32x4  __attribute__((ext_vector_type(4)));

__device__ __forceinline__ float bf2f(u16 u) {
    union { u32 i; float f; } v;
    v.i = ((u32)u) << 16;
    return v.f;
}
__device__ __forceinline__ u16 f2bf(float f) {
    union { float f; u32 i; } v;
    v.f = f;
    u32 x = v.i;
    x += 0x7fffu + ((x >> 16) & 1u);   // round to nearest even
    return (u16)(x >> 16);
}
// pack high-16s of two floats (truncating bf16): {lo=a, hi=b}
__device__ __forceinline__ u32 pack_bf_trunc(float a, float b) {
    return __builtin_amdgcn_perm(__float_as_uint(b), __float_as_uint(a),
                                 0x07060302u);
}

// async global->LDS, 16B per lane; ldsptr must be wave-uniform (HW adds lane*16)
typedef const __attribute__((address_space(1))) u32 gu32;
typedef __attribute__((address_space(3))) u32 lu32;
__device__ __forceinline__ void gload_lds16(const void* g, void* l) {
    __builtin_amdgcn_global_load_lds((gu32*)g, (lu32*)l, 16, 0, 0);
}

// ---------------------------------------------------------------------------
// 64x64 fp32->bf16 transpose tile helper (LDS tile passed in)
// ---------------------------------------------------------------------------
__device__ __forceinline__ void wt_tile(
    const float* __restrict__ W, u16* __restrict__ Wt,
    int K, int N, int t, int tid, float* tile /* 64*65 floats */)
{
    const int ntiles = N >> 6;
    const int n0 = (t % ntiles) * 64;
    const int k0 = (t / ntiles) * 64;

    int kr = tid >> 4;             // 0..15
    int nc = (tid & 15) * 4;       // 0..60
    #pragma unroll
    for (int p = 0; p < 4; ++p) {
        float4 v = *(const float4*)&W[(size_t)(k0 + kr + p * 16) * N + n0 + nc];
        tile[(kr + p * 16) * 65 + nc + 0] = v.x;
        tile[(kr + p * 16) * 65 + nc + 1] = v.y;
        tile[(kr + p * 16) * 65 + nc + 2] = v.z;
        tile[(kr + p * 16) * 65 + nc + 3] = v.w;
    }
    __syncthreads();

    int nr = tid >> 2;             // 0..63
    int kc = (tid & 3) * 16;       // 0..48
    u16 o[16];
    #pragma unroll
    for (int j = 0; j < 16; ++j) o[j] = f2bf(tile[(kc + j) * 65 + nr]);
    u16* dst = &Wt[(size_t)(n0 + nr) * K + k0 + kc];
    *(uint4*)dst       = *(const uint4*)&o[0];
    *(uint4*)(dst + 8) = *(const uint4*)&o[8];
}

// ---------------------------------------------------------------------------
// Prep: blocks [0,2048) convert x fp32->bf16; [2048,2816) transpose Wqkv.
// ---------------------------------------------------------------------------
__global__ __launch_bounds__(256) void prep_kernel(
    const float* __restrict__ x,    u16* __restrict__ xb,
    const float* __restrict__ Wqkv, u16* __restrict__ Wqkvt)
{
    __shared__ float tile[64 * 65];
    const int tid = threadIdx.x;
    const int bi  = blockIdx.x;

    if (bi < 2048) {   // x convert
        int i = bi * 2048 + tid * 8;
        float4 a = *(const float4*)(x + i);
        float4 b = *(const float4*)(x + i + 4);
        u16 o[8] = {f2bf(a.x), f2bf(a.y), f2bf(a.z), f2bf(a.w),
                    f2bf(b.x), f2bf(b.y), f2bf(b.z), f2bf(b.w)};
        *(uint4*)(xb + i) = *(const uint4*)o;
        return;
    }
    wt_tile(Wqkv, Wqkvt, 1024, 3072, bi - 2048, tid, tile);
}

// ---------------------------------------------------------------------------
// MFMA bf16 GEMM, m97-style, XCD remap, optional split-K (see R6/R7 notes).
// __launch_bounds__(256, 4): pin the allocator's occupancy target to 4
// waves/EU (= 4 blocks/CU, what split-K actually runs at; VGPR cap 128) —
// guards against the TU-level codegen drift seen in R11/R12 (VGPR 88->76,
// 51->63 us on identical source).
// EPI 0: scatter Q(x0.125*log2e)/K/V bf16 (out0v/out1/out2), N=3072
// EPI 2: ReLU, store out0v (OF32)
// EPI 3: bf16 partial (no bias) -> out0v[s*M*N + ...]
// ---------------------------------------------------------------------------
template <int EPI, int RF32, int OF32, int KS>
__global__ __launch_bounds__(256, 4) void gemm_bt_kernel(
    const u16* __restrict__ A, const u16* __restrict__ Bt,
    const float* __restrict__ bias, const void* __restrict__ resv,
    void* __restrict__ out0v, u16* __restrict__ out1, u16* __restrict__ out2,
    int M, int N, int K)
{
    __shared__ u16 sA[128 * 64];   // 16 KB, swizzled chunk layout
    __shared__ u16 sB[128 * 64];   // 16 KB

    const int tid  = threadIdx.x;
    const int lane = tid & 63;
    const int wave = tid >> 6;
    const int wm   = (wave & 1) * 64;
    const int wn   = (wave >> 1) * 64;
    const int quad = lane >> 4;
    const int l16  = lane & 15;

    // XCD-locality remap (requires gridDim.x % 2 == 0, gridDim.y % 4 == 0)
    const int nb  = gridDim.x;
    const int mb  = gridDim.y;
    const int f   = blockIdx.y * nb + blockIdx.x;   // dispatch-linear id
    const int xcd = f & 7;
    const int idx = f >> 3;
    const int rn  = nb >> 1;                        // region width  (tiles)
    const int rm  = mb >> 2;                        // region height (tiles)
    const int n0  = ((xcd & 1) * rn + (idx % rn)) * 128;
    const int ym  = (xcd >> 1) * rm + (idx / rn);   // 0..mb-1

    int s, m0;
    if (KS > 1) {
        const int mt = mb / KS;
        s  = ym / mt;
        m0 = (ym % mt) * 128;
    } else {
        s  = 0;
        m0 = ym * 128;
    }
    const int Kseg = K / KS;
    const int kbeg = s * Kseg;

    f32x4 acc[4][4];
    #pragma unroll
    for (int i = 0; i < 4; ++i)
        #pragma unroll
        for (int j = 0; j < 4; ++j)
            acc[i][j] = (f32x4){0.f, 0.f, 0.f, 0.f};

    const u16* Ablk = A  + (size_t)m0 * K;
    const u16* Bblk = Bt + (size_t)n0 * K;

    for (int k0 = kbeg; k0 < kbeg + Kseg; k0 += 64) {
        #pragma unroll
        for (int i = 0; i < 4; ++i) {
            int chunk = (i * 4 + wave) * 64 + lane;        // 0..1023
            int r = chunk >> 3;                            // row 0..127
            int c = (chunk & 7) ^ (r & 7);                 // swizzled k-chunk
            size_t goff = (size_t)r * K + k0 + c * 8;
            gload_lds16(Ablk + goff, &sA[(i * 4 + wave) * 512]);
            gload_lds16(Bblk + goff, &sB[(i * 4 + wave) * 512]);
        }
        __syncthreads();

        #pragma unroll
        for (int ks = 0; ks < 2; ++ks) {
            bf16x8 af[4], bfr[4];
            #pragma unroll
            for (int i = 0; i < 4; ++i) {
                int R = wm + i * 16 + l16;
                int slot = R * 8 + ((ks * 4 + quad) ^ (R & 7));
                af[i] = *(const bf16x8*)&sA[slot * 8];
            }
            #pragma unroll
            for (int j = 0; j < 4; ++j) {
                int R = wn + j * 16 + l16;
                int slot = R * 8 + ((ks * 4 + quad) ^ (R & 7));
                bfr[j] = *(const bf16x8*)&sB[slot * 8];
            }
            #pragma unroll
            for (int i = 0; i < 4; ++i)
                #pragma unroll
                for (int j = 0; j < 4; ++j)
                    acc[i][j] = __builtin_amdgcn_mfma_f32_16x16x32_bf16(
                        af[i], bfr[j], acc[i][j], 0, 0, 0);
        }
        __syncthreads();
    }

    #pragma unroll
    for (int i = 0; i < 4; ++i) {
        int rowb = m0 + wm + i * 16 + quad * 4;
        #pragma unroll
        for (int j = 0; j < 4; ++j) {
            int col = n0 + wn + j * 16 + l16;
            float bv = (EPI == 3) ? 0.f : bias[col];
            #pragma unroll
            for (int r = 0; r < 4; ++r) {
                int rr = rowb + r;
                float v = acc[i][j][r] + bv;
                if (EPI == 0) {
                    int which = col >> 10;
                    int h     = (col >> 6) & 15;
                    int d     = col & 63;
                    int b     = rr >> 11;
                    int l     = rr & 2047;
                    size_t idx2 = ((size_t)(b * NH + h) * LL + l) * DH + d;
                    u16* o0 = (u16*)out0v;
                    // Q pre-scaled by 0.125 * log2(e) so attention can use
                    // exp2 directly (softmax is scale-consistent).
                    if (which == 0)      o0[idx2]   = f2bf(v * 0.18033688f);
                    else if (which == 1) out1[idx2] = f2bf(v);
                    else                 out2[idx2] = f2bf(v);
                } else if (EPI == 3) {
                    ((u16*)out0v)[((size_t)s * M + rr) * N + col] = f2bf(v);
                } else {
                    size_t idx2 = (size_t)rr * N + col;
                    if (EPI == 1) {
                        v += RF32 ? ((const float*)resv)[idx2]
                                  : bf2f(((const u16*)resv)[idx2]);
                    } else {  // EPI == 2: ReLU
                        v = v > 0.f ? v : 0.f;
                    }
                    if (OF32) ((float*)out0v)[idx2] = v;
                    else      ((u16*)out0v)[idx2]   = f2bf(v);
                }
            }
        }
    }
}

// ---------------------------------------------------------------------------
// Fused split-K reduce + LayerNorm. One block per row.
// ---------------------------------------------------------------------------
template <int KS, int RF32, int OF32>
__global__ __launch_bounds__(256) void lnfuse_kernel(
    const u16* __restrict__ P, const float* __restrict__ bias,
    const void* __restrict__ resv,
    const float* __restrict__ ga, const float* __restrict__ gb,
    void* __restrict__ outv)
{
    __shared__ float red[8];
    const int tid  = threadIdx.x;
    const int lane = tid & 63;
    const int wave = tid >> 6;
    const size_t row = blockIdx.x;
    const size_t SL  = (size_t)MROWS * D_MODEL;
    const int c = tid * 4;

    float v0, v1, v2, v3;
    {
        float4 bv = *(const float4*)(bias + c);
        v0 = bv.x; v1 = bv.y; v2 = bv.z; v3 = bv.w;
    }
    #pragma unroll
    for (int s = 0; s < KS; ++s) {
        uint2 p = *(const uint2*)(P + s * SL + row * D_MODEL + c);
        v0 += bf2f((u16)p.x); v1 += bf2f((u16)(p.x >> 16));
        v2 += bf2f((u16)p.y); v3 += bf2f((u16)(p.y >> 16));
    }
    if (RF32) {
        float4 r = *(const float4*)((const float*)resv + row * D_MODEL + c);
        v0 += r.x; v1 += r.y; v2 += r.z; v3 += r.w;
    } else {
        uint2 r = *(const uint2*)((const u16*)resv + row * D_MODEL + c);
        v0 += bf2f((u16)r.x); v1 += bf2f((u16)(r.x >> 16));
        v2 += bf2f((u16)r.y); v3 += bf2f((u16)(r.y >> 16));
    }

    float s_ = v0 + v1 + v2 + v3;
    #pragma unroll
    for (int o = 32; o > 0; o >>= 1) s_ += __shfl_xor(s_, o, 64);
    if (lane == 0) red[wave] = s_;
    __syncthreads();
    float mean = (red[0] + red[1] + red[2] + red[3]) * (1.f / 1024.f);

    float d0 = v0 - mean, d1 = v1 - mean, d2 = v2 - mean, d3 = v3 - mean;
    float q = d0 * d0 + d1 * d1 + d2 * d2 + d3 * d3;
    #pragma unroll
    for (int o = 32; o > 0; o >>= 1) q += __shfl_xor(q, o, 64);
    if (lane == 0) red[4 + wave] = q;
    __syncthreads();
    float var = (red[4] + red[5] + red[6] + red[7]) * (1.f / 1023.f);
    float inv = 1.f / (sqrtf(var) + 1e-6f);

    float y0 = d0 * inv * ga[c + 0] + gb[c + 0];
    float y1 = d1 * inv * ga[c + 1] + gb[c + 1];
    float y2 = d2 * inv * ga[c + 2] + gb[c + 2];
    float y3 = d3 * inv * ga[c + 3] + gb[c + 3];
    if (OF32) {
        float4 y = {y0, y1, y2, y3};
        *(float4*)((float*)outv + row * D_MODEL + c) = y;
    } else {
        ushort4 y = {f2bf(y0), f2bf(y1), f2bf(y2), f2bf(y3)};
        *(ushort4*)((u16*)outv + row * D_MODEL + c) = y;
    }
}

// ---------------------------------------------------------------------------
// MFMA flash attention (causal, R9 structure) + FOLDED WEIGHT TRANSPOSES:
// blocks [0,512): attention (balanced pairs, XCD remap, register prefetch);
// blocks [512,2816): Wo/W1/W2 64x64 transpose tiles (fills idle CU slots).
// Softmax uses exp2 (Q pre-scaled by 0.125*log2e at QKV epilogue).
// ---------------------------------------------------------------------------
__global__ __launch_bounds__(256) void attn_kernel(
    const u16* __restrict__ Q, const u16* __restrict__ K,
    const u16* __restrict__ V, u16* __restrict__ out,
    const float* __restrict__ Wo, u16* __restrict__ Wot,
    const float* __restrict__ W1, u16* __restrict__ W1t,
    const float* __restrict__ W2, u16* __restrict__ W2t)
{
    __shared__ u16 smem[18432];   // 36864 B: ks|vs|ps for attn, tile for wt
    u16* ks = smem;                       // 64*72
    u16* vs = smem + 4608;                // 64*72
    u16* ps = smem + 9216;                // 4 waves * 2 tiles * 16*72

    const int tid  = threadIdx.x;
    const int bi   = blockIdx.x;

    if (bi >= 512) {   // ---- weight transpose blocks ----
        float* tile = (float*)smem;       // 64*65 floats = 16640 B
        int t = bi - 512;
        if (t < 256)       wt_tile(Wo, Wot, 1024, 1024, t,        tid, tile);
        else if (t < 1280) wt_tile(W1, W1t, 1024, 4096, t - 256,  tid, tile);
        else               wt_tile(W2, W2t, 4096, 1024, t - 1280, tid, tile);
        return;
    }

    const int lane = tid & 63;
    const int wave = tid >> 6;
    const int l16  = lane & 15;
    const int quad = lane >> 4;

    const int f   = bi;                 // 0..511
    const int xcd = f & 7;
    const int idx = f >> 3;             // 0..63
    const int bh  = xcd * 4 + (idx >> 4);
    const int pr  = idx & 15;
    const int b   = bh >> 4, h = bh & 15;
    const size_t head_off = (size_t)bh * LL * DH;

    const u16* Qh = Q + head_off;
    const u16* Kh = K + head_off;
    const u16* Vh = V + head_off;

    const int qtA = 31 - pr, qtB = pr;
    const int baseA = qtA * 64 + wave * 16;
    const int baseB = qtB * 64 + wave * 16;
    const int qgA   = baseA + l16;
    const int qgB   = baseB + l16;

    const bf16x8 qfA0 = *(const bf16x8*)&Qh[(size_t)qgA * DH + quad * 8];
    const bf16x8 qfA1 = *(const bf16x8*)&Qh[(size_t)qgA * DH + 32 + quad * 8];
    const bf16x8 qfB0 = *(const bf16x8*)&Qh[(size_t)qgB * DH + quad * 8];
    const bf16x8 qfB1 = *(const bf16x8*)&Qh[(size_t)qgB * DH + 32 + quad * 8];

    float lA = 0.f, lB = 0.f;
    f32x4 oA[4], oB[4];
    #pragma unroll
    for (int t = 0; t < 4; ++t) {
        oA[t] = (f32x4){0.f, 0.f, 0.f, 0.f};
        oB[t] = (f32x4){0.f, 0.f, 0.f, 0.f};
    }

    u16* psA = ps + wave * 2304;          // 2 * 16*72 per wave
    u16* psB = psA + 1152;

    const int key = tid >> 2;            // 0..63
    const int kd0 = (tid & 3) * 16;      // 0,16,32,48
    const int kp  = tid >> 3;            // 0..31 (key pair)
    const int vd0 = (tid & 7) * 8;       // 0..56

    uint4 kr0, kr1, vr0, vr1;
    {
        const u16* ksrc = Kh + (size_t)key * DH + kd0;
        kr0 = *(const uint4*)ksrc;
        kr1 = *(const uint4*)(ksrc + 8);
        const u16* vsrc = Vh + (size_t)(2 * kp) * DH + vd0;
        vr0 = *(const uint4*)vsrc;
        vr1 = *(const uint4*)(vsrc + DH);
    }

    for (int c = 0; c <= qtA; ++c) {
        const bool doB = (c <= qtB);
        __syncthreads();
        *(uint4*)&ks[key * 72 + kd0]     = kr0;
        *(uint4*)&ks[key * 72 + kd0 + 8] = kr1;
        {
            const u32* w0 = (const u32*)&vr0;
            const u32* w1 = (const u32*)&vr1;
            #pragma unroll
            for (int e = 0; e < 8; ++e) {
                int d = vd0 + e;
                u32 lo = (w0[e >> 1] >> ((e & 1) * 16)) & 0xffffu;
                u32 hi = (w1[e >> 1] >> ((e & 1) * 16)) & 0xffffu;
                int csw = kp ^ (4 * ((d >> 3) & 7));
                *(u32*)&vs[d * 72 + 2 * csw] = lo | (hi << 16);
            }
        }
        __syncthreads();
        if (c < qtA) {
            const u16* ksrc = Kh + (size_t)((c + 1) * 64 + key) * DH + kd0;
            kr0 = *(const uint4*)ksrc;
            kr1 = *(const uint4*)(ksrc + 8);
            const u16* vsrc = Vh + (size_t)((c + 1) * 64 + 2 * kp) * DH + vd0;
            vr0 = *(const uint4*)vsrc;
            vr1 = *(const uint4*)(vsrc + DH);
        }

        f32x4 stA[4], stB[4];
        #pragma unroll
        for (int t = 0; t < 4; ++t) {
            bf16x8 k0 = *(const bf16x8*)&ks[(t * 16 + l16) * 72 + quad * 8];
            bf16x8 k1 = *(const bf16x8*)&ks[(t * 16 + l16) * 72 + 32 + quad * 8];
            f32x4 s = (f32x4){0.f, 0.f, 0.f, 0.f};
            s = __builtin_amdgcn_mfma_f32_16x16x32_bf16(k0, qfA0, s, 0, 0, 0);
            s = __builtin_amdgcn_mfma_f32_16x16x32_bf16(k1, qfA1, s, 0, 0, 0);
            stA[t] = s;
            if (doB) {
                f32x4 s2 = (f32x4){0.f, 0.f, 0.f, 0.f};
                s2 = __builtin_amdgcn_mfma_f32_16x16x32_bf16(k0, qfB0, s2, 0, 0, 0);
                s2 = __builtin_amdgcn_mfma_f32_16x16x32_bf16(k1, qfB1, s2, 0, 0, 0);
                stB[t] = s2;
            }
        }

        if (c == qtA) {
            #pragma unroll
            for (int t = 0; t < 4; ++t)
                #pragma unroll
                for (int r = 0; r < 4; ++r)
                    if (c * 64 + t * 16 + quad * 4 + r > qgA) stA[t][r] = -INFINITY;
        }
        if (doB && c == qtB) {
            #pragma unroll
            for (int t = 0; t < 4; ++t)
                #pragma unroll
                for (int r = 0; r < 4; ++r)
                    if (c * 64 + t * 16 + quad * 4 + r > qgB) stB[t][r] = -INFINITY;
        }

        {
            float psum = 0.f;
            #pragma unroll
            for (int t = 0; t < 4; ++t) {
                float p0 = exp2f(stA[t][0]), p1 = exp2f(stA[t][1]);
                float p2 = exp2f(stA[t][2]), p3 = exp2f(stA[t][3]);
                psum += (p0 + p1) + (p2 + p3);
                uint2 w = {pack_bf_trunc(p0, p1), pack_bf_trunc(p2, p3)};
                *(uint2*)&psA[l16 * 72 + t * 16 + quad * 4] = w;
            }
            psum += __shfl_xor(psum, 16, 64);
            psum += __shfl_xor(psum, 32, 64);
            lA += psum;
        }
        if (doB) {
            float psum = 0.f;
            #pragma unroll
            for (int t = 0; t < 4; ++t) {
                float p0 = exp2f(stB[t][0]), p1 = exp2f(stB[t][1]);
                float p2 = exp2f(stB[t][2]), p3 = exp2f(stB[t][3]);
                psum += (p0 + p1) + (p2 + p3);
                uint2 w = {pack_bf_trunc(p0, p1), pack_bf_trunc(p2, p3)};
                *(uint2*)&psB[l16 * 72 + t * 16 + quad * 4] = w;
            }
            psum += __shfl_xor(psum, 16, 64);
            psum += __shfl_xor(psum, 32, 64);
            lB += psum;
        }

        bf16x8 pfA0 = *(const bf16x8*)&psA[l16 * 72 + quad * 8];
        bf16x8 pfA1 = *(const bf16x8*)&psA[l16 * 72 + 32 + quad * 8];
        bf16x8 pfB0, pfB1;
        if (doB) {
            pfB0 = *(const bf16x8*)&psB[l16 * 72 + quad * 8];
            pfB1 = *(const bf16x8*)&psB[l16 * 72 + 32 + quad * 8];
        }

        #pragma unroll
        for (int dt = 0; dt < 4; ++dt) {
            int d  = dt * 16 + l16;
            int sw = 4 * ((d >> 3) & 7);
            bf16x8 vf0 = *(const bf16x8*)&vs[d * 72 + 2 * ((quad * 4) ^ sw)];
            bf16x8 vf1 = *(const bf16x8*)&vs[d * 72 + 2 * ((16 + quad * 4) ^ sw)];
            oA[dt] = __builtin_amdgcn_mfma_f32_16x16x32_bf16(pfA0, vf0, oA[dt], 0, 0, 0);
            oA[dt] = __builtin_amdgcn_mfma_f32_16x16x32_bf16(pfA1, vf1, oA[dt], 0, 0, 0);
            if (doB) {
                oB[dt] = __builtin_amdgcn_mfma_f32_16x16x32_bf16(pfB0, vf0, oB[dt], 0, 0, 0);
                oB[dt] = __builtin_amdgcn_mfma_f32_16x16x32_bf16(pfB1, vf1, oB[dt], 0, 0, 0);
            }
        }
    }

    {
        float i0 = 1.f / __shfl(lA, quad * 4 + 0, 64);
        float i1 = 1.f / __shfl(lA, quad * 4 + 1, 64);
        float i2 = 1.f / __shfl(lA, quad * 4 + 2, 64);
        float i3 = 1.f / __shfl(lA, quad * 4 + 3, 64);
        #pragma unroll
        for (int dt = 0; dt < 4; ++dt) {
            size_t col = h * DH + dt * 16 + l16;
            size_t r0  = ((size_t)b * LL + baseA + quad * 4) * D_MODEL + col;
            out[r0]               = f2bf(oA[dt][0] * i0);
            out[r0 + D_MODEL]     = f2bf(oA[dt][1] * i1);
            out[r0 + 2 * D_MODEL] = f2bf(oA[dt][2] * i2);
            out[r0 + 3 * D_MODEL] = f2bf(oA[dt][3] * i3);
        }
    }
    {
        float i0 = 1.f / __shfl(lB, quad * 4 + 0, 64);
        float i1 = 1.f / __shfl(lB, quad * 4 + 1, 64);
        float i2 = 1.f / __shfl(lB, quad * 4 + 2, 64);
        float i3 = 1.f / __shfl(lB, quad * 4 + 3, 64);
        #pragma unroll
        for (int dt = 0; dt < 4; ++dt) {
            size_t col = h * DH + dt * 16 + l16;
            size_t r0  = ((size_t)b * LL + baseB + quad * 4) * D_MODEL + col;
            out[r0]               = f2bf(oB[dt][0] * i0);
            out[r0 + D_MODEL]     = f2bf(oB[dt][1] * i1);
            out[r0 + 2 * D_MODEL] = f2bf(oB[dt][2] * i2);
            out[r0 + 3 * D_MODEL] = f2bf(oB[dt][3] * i3);
        }
    }
}

// ---------------------------------------------------------------------------
extern "C" void kernel_launch(void* const* d_in, const int* in_sizes, int n_in,
                              void* d_out, int out_size, void* d_ws, size_t ws_size,
                              hipStream_t stream)
{
    const float* x    = (const float*)d_in[0];
    // d_in[1] = mask (int32) — causal, handled analytically
    const float* Wqkv = (const float*)d_in[2];
    const float* bqkv = (const float*)d_in[3];
    const float* Wo   = (const float*)d_in[4];
    const float* bo   = (const float*)d_in[5];
    const float* W1   = (const float*)d_in[6];
    const float* b1   = (const float*)d_in[7];
    const float* W2   = (const float*)d_in[8];
    const float* b2   = (const float*)d_in[9];
    const float* ln1a = (const float*)d_in[10];
    const float* ln1b = (const float*)d_in[11];
    const float* ln2a = (const float*)d_in[12];
    const float* ln2b = (const float*)d_in[13];

    char* ws = (char*)d_ws;
    const size_t HSZ = (size_t)BB * NH * LL * DH;      // 4,194,304 elems
    u16*   Qp    = (u16*)ws;
    u16*   Kp    = Qp + HSZ;
    u16*   Vp    = Kp + HSZ;
    u16*   attn  = Vp + HSZ;
    u16*   hbuf  = (u16*)ws;                               // alias (QKV/attn dead)
    u16*   xb    = (u16*)(ws + 33554432);                  // bf16 x, 8 MB
    u16*   x1    = (u16*)(ws + 50331648);                  // bf16, 8 MB
    u16*   Wqkvt = (u16*)(ws + 58720256);                  // 3072x1024 bf16
    u16*   Wot   = (u16*)(ws + 65011712);                  // 1024x1024 bf16
    u16*   W1t   = (u16*)(ws + 67108864);                  // 4096x1024 bf16
    u16*   W2t   = (u16*)(ws + 75497472);                  // 1024x4096 bf16
    u16*   Pbuf  = (u16*)(ws + 83886080);                  // up to 4x 4096x1024 bf16

    dim3 blk(256);

    // 0) prep: x->bf16 + Wqkv transpose (only what QKV GEMM needs)
    prep_kernel<<<dim3(2816), blk, 0, stream>>>(x, xb, Wqkv, Wqkvt);

    // 1) qkv = x @ Wqkv + bqkv -> scatter Q(*0.125*log2e), K, V (bf16)
    gemm_bt_kernel<0,0,0,1><<<dim3(24, 32), blk, 0, stream>>>(
        xb, Wqkvt, bqkv, nullptr, Qp, Kp, Vp, MROWS, 3 * D_MODEL, D_MODEL);
    // 2) attention -> attn bf16; folds Wo/W1/W2 transposes into idle slots
    attn_kernel<<<dim3(2816), blk, 0, stream>>>(
        Qp, Kp, Vp, attn, Wo, Wot, W1, W1t, W2, W2t);
    // 3) Wo partials (split-K=2)
    gemm_bt_kernel<3,0,0,2><<<dim3(8, 64), blk, 0, stream>>>(
        attn, Wot, bo, nullptr, Pbuf, nullptr, nullptr, MROWS, D_MODEL, D_MODEL);
    // 4) x1 = LN1(sum(P) + bo + x)  (fused reduce+LN, bf16 out)
    lnfuse_kernel<2,1,0><<<dim3(MROWS), blk, 0, stream>>>(
        Pbuf, bo, x, ln1a, ln1b, x1);
    // 5) h = relu(x1 @ W1 + b1)  (bf16 out)
    gemm_bt_kernel<2,0,0,1><<<dim3(32, 32), blk, 0, stream>>>(
        x1, W1t, b1, nullptr, hbuf, nullptr, nullptr, MROWS, D_FFN, D_MODEL);
    // 6) W2 partials (split-K=4)
    gemm_bt_kernel<3,0,0,4><<<dim3(8, 128), blk, 0, stream>>>(
        hbuf, W2t, b2, nullptr, Pbuf, nullptr, nullptr, MROWS, D_MODEL, D_FFN);
    // 7) out = LN2(sum(P) + b2 + x1)  (fused reduce+LN, fp32 out)
    lnfuse_kernel<4,0,1><<<dim3(MROWS), blk, 0, stream>>>(
        Pbuf, b2, x1, ln2a, ln2b, d_out);
}